// Round 2
// baseline (644.948 us; speedup 1.0000x reference)
//
#include <hip/hip_runtime.h>
#include <hip/hip_bf16.h>

#define NB 262144
#define RTILE 64

typedef __bf16 bf16x8 __attribute__((ext_vector_type(8)));
typedef float f32x4 __attribute__((ext_vector_type(4)));

// ---- packed bf16 weight buffer (module-global, rewritten every launch) ----
// Layout: row-major [N][Kpad], K zero-padded to multiple of 32.
#define OFF_W0   0        // [256][64]   (K 63->64)
#define OFF_W1   16384    // [256][256]
#define OFF_W2   81920
#define OFF_W3   147456
#define OFF_W4   212992
#define OFF_W5   278528   // [256][320]  (K 319->320)
#define OFF_W6   360448
#define OFF_W7   425984
#define OFF_WSIG 491520   // [1][256]
#define OFF_W8   491776   // [256][256]
#define OFF_W9   557312   // [128][288]  (K 283->288)
#define OFF_W10  594176   // [128][128]
#define OFF_W11  610560
#define OFF_W12  626944
#define OFF_WRGB 643328   // [3][128]
#define WTOTAL   643712

__device__ __align__(16) unsigned short g_w[WTOTAL];

__device__ __forceinline__ unsigned short f2bfu(float f) {
  __bf16 h = (__bf16)f;
  return __builtin_bit_cast(unsigned short, h);
}
__device__ __forceinline__ float bfu2f(unsigned short u) {
  return (float)__builtin_bit_cast(__bf16, u);
}

__global__ void prep_kernel(const float* W0, const float* W1, const float* W2,
                            const float* W3, const float* W4, const float* W5,
                            const float* W6, const float* W7, const float* Wsig,
                            const float* W8, const float* W9, const float* W10,
                            const float* W11, const float* W12, const float* Wrgb) {
  const float* srcs[15] = {W0,W1,W2,W3,W4,W5,W6,W7,Wsig,W8,W9,W10,W11,W12,Wrgb};
  const int dsto[16] = {OFF_W0,OFF_W1,OFF_W2,OFF_W3,OFF_W4,OFF_W5,OFF_W6,OFF_W7,
                        OFF_WSIG,OFF_W8,OFF_W9,OFF_W10,OFF_W11,OFF_W12,OFF_WRGB,WTOTAL};
  const int kpad[15] = {64,256,256,256,256,320,256,256,256,256,288,128,128,128,128};
  const int ksrc[15] = {63,256,256,256,256,319,256,256,256,256,283,128,128,128,128};
  int idx = blockIdx.x * blockDim.x + threadIdx.x;
  if (idx >= WTOTAL) return;
  int r = 0;
  for (int i = 1; i < 15; ++i) if (idx >= dsto[i]) r = i;
  int local = idx - dsto[r];
  int o = local / kpad[r];
  int k = local - o * kpad[r];
  float v = (k < ksrc[r]) ? srcs[r][o * ksrc[r] + k] : 0.0f;
  g_w[idx] = f2bfu(v);
}

// ---- fused MLP ----
// Block: 256 threads = 4 waves, 64 rows. Activations ping-pong in LDS (bf16,
// stride 264 -> 528B row stride -> 4-bank shift/row -> <=2-way conflict, free).
// Each wave owns a (NT*16)-wide column stripe; MFMA 16x16x32 bf16,
// C/D: col=lane&15, row=(lane>>4)*4+i (m89-verified).
template<int KS1, int KS2, int NT, bool RELU>
__device__ __forceinline__ void gemm_layer(
    const unsigned short* A1, int sA1,
    const unsigned short* A2, int sA2,
    const unsigned short* Wp, int Kpad,
    const float* bias,
    unsigned short* Out, int sO,
    int lane, int wid)
{
  const int l15 = lane & 15;
  const int l4  = lane >> 4;
  const int colbase = wid * (NT * 16);
  f32x4 acc[4][NT];
#pragma unroll
  for (int rt = 0; rt < 4; ++rt)
#pragma unroll
    for (int ct = 0; ct < NT; ++ct)
      acc[rt][ct] = (f32x4){0.f, 0.f, 0.f, 0.f};

#pragma unroll
  for (int kk = 0; kk < KS1 + KS2; ++kk) {
    bf16x8 a[4];
    if (kk < KS1) {
      const int koff = kk * 32 + l4 * 8;
#pragma unroll
      for (int rt = 0; rt < 4; ++rt)
        a[rt] = *(const bf16x8*)&A1[(rt * 16 + l15) * sA1 + koff];
    } else {
      const int koff = (kk - KS1) * 32 + l4 * 8;
#pragma unroll
      for (int rt = 0; rt < 4; ++rt)
        a[rt] = *(const bf16x8*)&A2[(rt * 16 + l15) * sA2 + koff];
    }
    bf16x8 b[NT];
    const int kg = kk * 32 + l4 * 8;
#pragma unroll
    for (int ct = 0; ct < NT; ++ct) {
      const int o = colbase + ct * 16 + l15;
      b[ct] = *(const bf16x8*)&Wp[o * Kpad + kg];
    }
#pragma unroll
    for (int ct = 0; ct < NT; ++ct)
#pragma unroll
      for (int rt = 0; rt < 4; ++rt)
        acc[rt][ct] = __builtin_amdgcn_mfma_f32_16x16x32_bf16(a[rt], b[ct], acc[rt][ct], 0, 0, 0);
  }

#pragma unroll
  for (int ct = 0; ct < NT; ++ct) {
    const int col = colbase + ct * 16 + l15;
    const float bv = bias[col];
#pragma unroll
    for (int rt = 0; rt < 4; ++rt) {
#pragma unroll
      for (int i = 0; i < 4; ++i) {
        const int row = rt * 16 + l4 * 4 + i;
        float v = acc[rt][ct][i] + bv;
        if (RELU) v = fmaxf(v, 0.0f);
        Out[row * sO + col] = f2bfu(v);
      }
    }
  }
}

__launch_bounds__(256, 2)
__global__ void nerf_main(const float* __restrict__ x, const float* __restrict__ d,
    const float* b0, const float* b1, const float* b2, const float* b3,
    const float* b4, const float* b5, const float* b6, const float* b7,
    const float* bsig, const float* b8, const float* b9, const float* b10,
    const float* b11, const float* b12, const float* brgb,
    float* __restrict__ out)
{
  __shared__ unsigned short Ha[64][264];
  __shared__ unsigned short Hb[64][264];
  __shared__ unsigned short Xb[64][72];   // x tile, col 63 = 0 (K pad)
  __shared__ unsigned short Db[64][40];   // d tile, cols 27..31 = 0

  const int tid = threadIdx.x;
  const int lane = tid & 63;
  const int wid = tid >> 6;
  const int rowbase = blockIdx.x * RTILE;

  // ---- stage x and d tiles (fp32 -> bf16) ----
  {
    const int r = tid >> 2;      // 0..63
    const int sub = tid & 3;
    const float* xr = x + (size_t)(rowbase + r) * 63;
    for (int j = 0; j < 16; ++j) {
      const int c = sub + j * 4;        // 0..63
      Xb[r][c] = (c < 63) ? f2bfu(xr[c]) : (unsigned short)0;
    }
    const float* dr = d + (size_t)(rowbase + r) * 27;
    for (int j = 0; j < 8; ++j) {
      const int c = sub + j * 4;        // 0..31
      Db[r][c] = (c < 27) ? f2bfu(dr[c]) : (unsigned short)0;
    }
  }
  __syncthreads();

  gemm_layer<2,0,4,true >(&Xb[0][0], 72, nullptr, 0, g_w + OFF_W0, 64,  b0, &Ha[0][0], 264, lane, wid);
  __syncthreads();
  gemm_layer<8,0,4,true >(&Ha[0][0], 264, nullptr, 0, g_w + OFF_W1, 256, b1, &Hb[0][0], 264, lane, wid);
  __syncthreads();
  gemm_layer<8,0,4,true >(&Hb[0][0], 264, nullptr, 0, g_w + OFF_W2, 256, b2, &Ha[0][0], 264, lane, wid);
  __syncthreads();
  gemm_layer<8,0,4,true >(&Ha[0][0], 264, nullptr, 0, g_w + OFF_W3, 256, b3, &Hb[0][0], 264, lane, wid);
  __syncthreads();
  gemm_layer<8,0,4,true >(&Hb[0][0], 264, nullptr, 0, g_w + OFF_W4, 256, b4, &Ha[0][0], 264, lane, wid);
  __syncthreads();
  // L5: concat [h(256) | x(63)+pad] -> K=320
  gemm_layer<8,2,4,true >(&Ha[0][0], 264, &Xb[0][0], 72, g_w + OFF_W5, 320, b5, &Hb[0][0], 264, lane, wid);
  __syncthreads();
  gemm_layer<8,0,4,true >(&Hb[0][0], 264, nullptr, 0, g_w + OFF_W6, 256, b6, &Ha[0][0], 264, lane, wid);
  __syncthreads();
  gemm_layer<8,0,4,true >(&Ha[0][0], 264, nullptr, 0, g_w + OFF_W7, 256, b7, &Hb[0][0], 264, lane, wid);
  __syncthreads();

  // ---- sigma head: softplus(h7 @ Wsig + bsig), h7 in Hb ----
  {
    const int r = tid >> 2;
    const int part = tid & 3;
    float s = 0.f;
    const unsigned short* wrow = g_w + OFF_WSIG + part * 64;
    const unsigned short* hrow = &Hb[r][part * 64];
#pragma unroll 8
    for (int k = 0; k < 64; ++k)
      s += bfu2f(hrow[k]) * bfu2f(wrow[k]);
    s += __shfl_xor(s, 1);
    s += __shfl_xor(s, 2);
    if (part == 0) {
      float logit = s + bsig[0];
      float sp = (logit > 0.f) ? (logit + log1pf(expf(-logit))) : log1pf(expf(logit));
      out[3 * NB + rowbase + r] = sp;
    }
  }

  // L8 (bottleneck, no relu): Hb -> Ha
  gemm_layer<8,0,4,false>(&Hb[0][0], 264, nullptr, 0, g_w + OFF_W8, 256, b8, &Ha[0][0], 264, lane, wid);
  __syncthreads();

  // L9: concat [h8(256) | d(27)+pad] -> K=288, N=128
  gemm_layer<8,1,2,true >(&Ha[0][0], 264, &Db[0][0], 40, g_w + OFF_W9, 288, b9, &Hb[0][0], 264, lane, wid);
  __syncthreads();
  gemm_layer<4,0,2,true >(&Hb[0][0], 264, nullptr, 0, g_w + OFF_W10, 128, b10, &Ha[0][0], 264, lane, wid);
  __syncthreads();
  gemm_layer<4,0,2,true >(&Ha[0][0], 264, nullptr, 0, g_w + OFF_W11, 128, b11, &Hb[0][0], 264, lane, wid);
  __syncthreads();
  gemm_layer<4,0,2,true >(&Hb[0][0], 264, nullptr, 0, g_w + OFF_W12, 128, b12, &Ha[0][0], 264, lane, wid);
  __syncthreads();

  // ---- rgb head: sigmoid(h12 @ Wrgb + brgb), h12 in Ha (cols 0..127) ----
  if (tid < 192) {
    const int r = tid / 3;
    const int ch = tid - r * 3;
    float s = 0.f;
    const unsigned short* wrow = g_w + OFF_WRGB + ch * 128;
#pragma unroll 8
    for (int k = 0; k < 128; ++k)
      s += bfu2f(Ha[r][k]) * bfu2f(wrow[k]);
    float logit = s + brgb[ch];
    float val = 1.f / (1.f + expf(-logit));
    out[(size_t)(rowbase + r) * 3 + ch] = val;
  }
}

extern "C" void kernel_launch(void* const* d_in, const int* in_sizes, int n_in,
                              void* d_out, int out_size, void* d_ws, size_t ws_size,
                              hipStream_t stream) {
  const float* x    = (const float*)d_in[0];
  const float* dd   = (const float*)d_in[1];
  const float* W0   = (const float*)d_in[2];
  const float* b0   = (const float*)d_in[3];
  const float* W1   = (const float*)d_in[4];
  const float* b1   = (const float*)d_in[5];
  const float* W2   = (const float*)d_in[6];
  const float* b2   = (const float*)d_in[7];
  const float* W3   = (const float*)d_in[8];
  const float* b3   = (const float*)d_in[9];
  const float* W4   = (const float*)d_in[10];
  const float* b4   = (const float*)d_in[11];
  const float* W5   = (const float*)d_in[12];
  const float* b5   = (const float*)d_in[13];
  const float* W6   = (const float*)d_in[14];
  const float* b6   = (const float*)d_in[15];
  const float* W7   = (const float*)d_in[16];
  const float* b7   = (const float*)d_in[17];
  const float* Wsig = (const float*)d_in[18];
  const float* bsig = (const float*)d_in[19];
  const float* W8   = (const float*)d_in[20];
  const float* b8   = (const float*)d_in[21];
  const float* W9   = (const float*)d_in[22];
  const float* b9   = (const float*)d_in[23];
  const float* W10  = (const float*)d_in[24];
  const float* b10  = (const float*)d_in[25];
  const float* W11  = (const float*)d_in[26];
  const float* b11  = (const float*)d_in[27];
  const float* W12  = (const float*)d_in[28];
  const float* b12  = (const float*)d_in[29];
  const float* Wrgb = (const float*)d_in[30];
  const float* brgb = (const float*)d_in[31];

  prep_kernel<<<(WTOTAL + 255) / 256, 256, 0, stream>>>(
      W0, W1, W2, W3, W4, W5, W6, W7, Wsig, W8, W9, W10, W11, W12, Wrgb);

  nerf_main<<<NB / RTILE, 256, 0, stream>>>(
      x, dd, b0, b1, b2, b3, b4, b5, b6, b7, bsig, b8, b9, b10, b11, b12, brgb,
      (float*)d_out);
}

// Round 3
// 346.335 us; speedup vs baseline: 1.8622x; 1.8622x over previous
//
#include <hip/hip_runtime.h>
#include <hip/hip_bf16.h>

#define NB 262144
#define RTILE 64

typedef __bf16 bf16x8 __attribute__((ext_vector_type(8)));
typedef float f32x4 __attribute__((ext_vector_type(4)));

// ---- packed bf16 weight buffer ----
// MFMA layers are stored FRAGMENT-ORDERED: for layer with Ntiles=N/16 col-tiles
// and KS=Kpad/32 K-steps, fragment (colTile,ks) lives at
//   off + ((colTile*KS + ks)*64 + lane)*8  (8 bf16 per lane)
// where lane's elements are W[col=colTile*16+(lane&15)][k=ks*32+(lane>>4)*8+e].
// This makes each wave's B-fragment load one contiguous 1KB burst.
// Wsig/Wrgb (head weights) stay plain row-major.
#define OFF_W0   0        // [256][64]   (K 63->64)
#define OFF_W1   16384    // [256][256]
#define OFF_W2   81920
#define OFF_W3   147456
#define OFF_W4   212992
#define OFF_W5   278528   // [256][320]  (K 319->320)
#define OFF_W6   360448
#define OFF_W7   425984
#define OFF_WSIG 491520   // [1][256] plain
#define OFF_W8   491776   // [256][256]
#define OFF_W9   557312   // [128][288]  (K 283->288)
#define OFF_W10  594176   // [128][128]
#define OFF_W11  610560
#define OFF_W12  626944
#define OFF_WRGB 643328   // [3][128] plain
#define WTOTAL   643712

__device__ __align__(16) unsigned short g_w[WTOTAL];

__device__ __forceinline__ unsigned short f2bfu(float f) {
  __bf16 h = (__bf16)f;
  return __builtin_bit_cast(unsigned short, h);
}
__device__ __forceinline__ float bfu2f(unsigned short u) {
  return (float)__builtin_bit_cast(__bf16, u);
}

__global__ void prep_kernel(const float* W0, const float* W1, const float* W2,
                            const float* W3, const float* W4, const float* W5,
                            const float* W6, const float* W7, const float* Wsig,
                            const float* W8, const float* W9, const float* W10,
                            const float* W11, const float* W12, const float* Wrgb) {
  const float* srcs[15] = {W0,W1,W2,W3,W4,W5,W6,W7,Wsig,W8,W9,W10,W11,W12,Wrgb};
  const int dsto[16] = {OFF_W0,OFF_W1,OFF_W2,OFF_W3,OFF_W4,OFF_W5,OFF_W6,OFF_W7,
                        OFF_WSIG,OFF_W8,OFF_W9,OFF_W10,OFF_W11,OFF_W12,OFF_WRGB,WTOTAL};
  const int kpad[15] = {64,256,256,256,256,320,256,256,256,256,288,128,128,128,128};
  const int ksrc[15] = {63,256,256,256,256,319,256,256,256,256,283,128,128,128,128};
  int idx = blockIdx.x * blockDim.x + threadIdx.x;
  if (idx >= WTOTAL) return;
  int r = 0;
  for (int i = 1; i < 15; ++i) if (idx >= dsto[i]) r = i;
  int local = idx - dsto[r];
  float v;
  if (r == 8 || r == 14) {             // head weights: plain row-major
    int o = local / kpad[r];
    int k = local - o * kpad[r];
    v = (k < ksrc[r]) ? srcs[r][o * ksrc[r] + k] : 0.0f;
  } else {                             // MFMA layers: fragment-ordered
    const int KS = kpad[r] >> 5;       // Kpad/32
    int frag = local >> 9;             // /512 elements per fragment
    int within = local & 511;
    int lane = within >> 3;
    int e = within & 7;
    int colTile = frag / KS;
    int ks = frag - colTile * KS;
    int col = colTile * 16 + (lane & 15);
    int k = ks * 32 + (lane >> 4) * 8 + e;
    v = (k < ksrc[r]) ? srcs[r][col * ksrc[r] + k] : 0.0f;
  }
  g_w[idx] = f2bfu(v);
}

// ---- fused MLP ----
// Block: 256 threads = 4 waves, 64 rows. SINGLE activation buffer H in LDS:
// each layer = {compute into regs (read all of H), barrier, write own stripe,
// barrier}. 48.1KB LDS -> 3 blocks/CU (12 waves) for latency hiding.
// MFMA 16x16x32 bf16, C/D: col=lane&15, row=(lane>>4)*4+i (m89-verified).
template<int KS1, int KS2, int NT>
__device__ __forceinline__ void gemm_compute(
    const unsigned short* A1, int sA1,
    const unsigned short* A2, int sA2,
    const unsigned short* Wp,           // fragment-ordered layer base
    f32x4 (&acc)[4][NT],
    int lane, int wid)
{
  const int l15 = lane & 15;
  const int l4  = lane >> 4;
  constexpr int KS = KS1 + KS2;
  const unsigned short* wb = Wp + (size_t)(wid * NT) * KS * 512 + lane * 8;

#pragma unroll
  for (int rt = 0; rt < 4; ++rt)
#pragma unroll
    for (int ct = 0; ct < NT; ++ct)
      acc[rt][ct] = (f32x4){0.f, 0.f, 0.f, 0.f};

#pragma unroll
  for (int kk = 0; kk < KS; ++kk) {
    bf16x8 a[4];
    if (kk < KS1) {
      const int koff = kk * 32 + l4 * 8;
#pragma unroll
      for (int rt = 0; rt < 4; ++rt)
        a[rt] = *(const bf16x8*)&A1[(rt * 16 + l15) * sA1 + koff];
    } else {
      const int koff = (kk - KS1) * 32 + l4 * 8;
#pragma unroll
      for (int rt = 0; rt < 4; ++rt)
        a[rt] = *(const bf16x8*)&A2[(rt * 16 + l15) * sA2 + koff];
    }
    bf16x8 b[NT];
#pragma unroll
    for (int ct = 0; ct < NT; ++ct)
      b[ct] = *(const bf16x8*)&wb[(size_t)(ct * KS + kk) * 512];
#pragma unroll
    for (int ct = 0; ct < NT; ++ct)
#pragma unroll
      for (int rt = 0; rt < 4; ++rt)
        acc[rt][ct] = __builtin_amdgcn_mfma_f32_16x16x32_bf16(a[rt], b[ct], acc[rt][ct], 0, 0, 0);
  }
}

template<int NT, bool RELU>
__device__ __forceinline__ void store_acc(
    const f32x4 (&acc)[4][NT], const float* bias,
    unsigned short* Out, int sO, int lane, int wid)
{
  const int l15 = lane & 15;
  const int l4  = lane >> 4;
  const int colbase = wid * (NT * 16);
#pragma unroll
  for (int ct = 0; ct < NT; ++ct) {
    const int col = colbase + ct * 16 + l15;
    const float bv = bias[col];
#pragma unroll
    for (int rt = 0; rt < 4; ++rt) {
#pragma unroll
      for (int i = 0; i < 4; ++i) {
        const int row = rt * 16 + l4 * 4 + i;
        float v = acc[rt][ct][i] + bv;
        if (RELU) v = fmaxf(v, 0.0f);
        Out[row * sO + col] = f2bfu(v);
      }
    }
  }
}

__launch_bounds__(256, 3)
__global__ void nerf_main(const float* __restrict__ x, const float* __restrict__ d,
    const float* b0, const float* b1, const float* b2, const float* b3,
    const float* b4, const float* b5, const float* b6, const float* b7,
    const float* bsig, const float* b8, const float* b9, const float* b10,
    const float* b11, const float* b12, const float* brgb,
    float* __restrict__ out)
{
  __shared__ unsigned short H[64][264];   // single activation buffer
  __shared__ unsigned short Xb[64][72];   // x tile, col 63 = 0 (K pad)
  __shared__ unsigned short Db[64][40];   // d tile, cols 27..31 = 0

  const int tid = threadIdx.x;
  const int lane = tid & 63;
  const int wid = tid >> 6;
  const int rowbase = blockIdx.x * RTILE;

  // ---- stage x and d tiles (fp32 -> bf16) ----
  {
    const int r = tid >> 2;      // 0..63
    const int sub = tid & 3;
    const float* xr = x + (size_t)(rowbase + r) * 63;
    for (int j = 0; j < 16; ++j) {
      const int c = sub + j * 4;        // 0..63
      Xb[r][c] = (c < 63) ? f2bfu(xr[c]) : (unsigned short)0;
    }
    const float* dr = d + (size_t)(rowbase + r) * 27;
    for (int j = 0; j < 8; ++j) {
      const int c = sub + j * 4;        // 0..31
      Db[r][c] = (c < 27) ? f2bfu(dr[c]) : (unsigned short)0;
    }
  }
  __syncthreads();

  f32x4 acc4[4][4];
  f32x4 acc2[4][2];

  // L0: reads Xb only -> can write H immediately (first writer)
  gemm_compute<2,0,4>(&Xb[0][0], 72, nullptr, 0, g_w + OFF_W0, acc4, lane, wid);
  store_acc<4,true>(acc4, b0, &H[0][0], 264, lane, wid);
  __syncthreads();

#define BIG_LAYER(OFFW, BIAS) \
  gemm_compute<8,0,4>(&H[0][0], 264, nullptr, 0, g_w + OFFW, acc4, lane, wid); \
  __syncthreads(); \
  store_acc<4,true>(acc4, BIAS, &H[0][0], 264, lane, wid); \
  __syncthreads();

  BIG_LAYER(OFF_W1, b1)
  BIG_LAYER(OFF_W2, b2)
  BIG_LAYER(OFF_W3, b3)
  BIG_LAYER(OFF_W4, b4)

  // L5: concat [h(256) | x(63)+pad] -> K=320
  gemm_compute<8,2,4>(&H[0][0], 264, &Xb[0][0], 72, g_w + OFF_W5, acc4, lane, wid);
  __syncthreads();
  store_acc<4,true>(acc4, b5, &H[0][0], 264, lane, wid);
  __syncthreads();

  BIG_LAYER(OFF_W6, b6)
  BIG_LAYER(OFF_W7, b7)

  // ---- sigma head: softplus(h7 @ Wsig + bsig), h7 in H ----
  {
    const int r = tid >> 2;
    const int part = tid & 3;
    float s = 0.f;
    const unsigned short* wrow = g_w + OFF_WSIG + part * 64;
    const unsigned short* hrow = &H[r][part * 64];
#pragma unroll 8
    for (int k = 0; k < 64; ++k)
      s += bfu2f(hrow[k]) * bfu2f(wrow[k]);
    s += __shfl_xor(s, 1);
    s += __shfl_xor(s, 2);
    if (part == 0) {
      float logit = s + bsig[0];
      float sp = (logit > 0.f) ? (logit + log1pf(expf(-logit))) : log1pf(expf(logit));
      out[3 * NB + rowbase + r] = sp;
    }
  }

  // L8 (bottleneck, no relu)
  gemm_compute<8,0,4>(&H[0][0], 264, nullptr, 0, g_w + OFF_W8, acc4, lane, wid);
  __syncthreads();                // also covers sigma-head reads of H
  store_acc<4,false>(acc4, b8, &H[0][0], 264, lane, wid);
  __syncthreads();

  // L9: concat [h8(256) | d(27)+pad] -> K=288, N=128
  gemm_compute<8,1,2>(&H[0][0], 264, &Db[0][0], 40, g_w + OFF_W9, acc2, lane, wid);
  __syncthreads();
  store_acc<2,true>(acc2, b9, &H[0][0], 264, lane, wid);
  __syncthreads();

#define SMALL_LAYER(OFFW, BIAS) \
  gemm_compute<4,0,2>(&H[0][0], 264, nullptr, 0, g_w + OFFW, acc2, lane, wid); \
  __syncthreads(); \
  store_acc<2,true>(acc2, BIAS, &H[0][0], 264, lane, wid); \
  __syncthreads();

  SMALL_LAYER(OFF_W10, b10)
  SMALL_LAYER(OFF_W11, b11)
  SMALL_LAYER(OFF_W12, b12)

  // ---- rgb head: sigmoid(h12 @ Wrgb + brgb), h12 in H cols 0..127 ----
  if (tid < 192) {
    const int r = tid / 3;
    const int ch = tid - r * 3;
    float s = 0.f;
    const unsigned short* wrow = g_w + OFF_WRGB + ch * 128;
#pragma unroll 8
    for (int k = 0; k < 128; ++k)
      s += bfu2f(H[r][k]) * bfu2f(wrow[k]);
    float logit = s + brgb[ch];
    float val = 1.f / (1.f + expf(-logit));
    out[(size_t)(rowbase + r) * 3 + ch] = val;
  }
}

extern "C" void kernel_launch(void* const* d_in, const int* in_sizes, int n_in,
                              void* d_out, int out_size, void* d_ws, size_t ws_size,
                              hipStream_t stream) {
  const float* x    = (const float*)d_in[0];
  const float* dd   = (const float*)d_in[1];
  const float* W0   = (const float*)d_in[2];
  const float* b0   = (const float*)d_in[3];
  const float* W1   = (const float*)d_in[4];
  const float* b1   = (const float*)d_in[5];
  const float* W2   = (const float*)d_in[6];
  const float* b2   = (const float*)d_in[7];
  const float* W3   = (const float*)d_in[8];
  const float* b3   = (const float*)d_in[9];
  const float* W4   = (const float*)d_in[10];
  const float* b4   = (const float*)d_in[11];
  const float* W5   = (const float*)d_in[12];
  const float* b5   = (const float*)d_in[13];
  const float* W6   = (const float*)d_in[14];
  const float* b6   = (const float*)d_in[15];
  const float* W7   = (const float*)d_in[16];
  const float* b7   = (const float*)d_in[17];
  const float* Wsig = (const float*)d_in[18];
  const float* bsig = (const float*)d_in[19];
  const float* W8   = (const float*)d_in[20];
  const float* b8   = (const float*)d_in[21];
  const float* W9   = (const float*)d_in[22];
  const float* b9   = (const float*)d_in[23];
  const float* W10  = (const float*)d_in[24];
  const float* b10  = (const float*)d_in[25];
  const float* W11  = (const float*)d_in[26];
  const float* b11  = (const float*)d_in[27];
  const float* W12  = (const float*)d_in[28];
  const float* b12  = (const float*)d_in[29];
  const float* Wrgb = (const float*)d_in[30];
  const float* brgb = (const float*)d_in[31];

  prep_kernel<<<(WTOTAL + 255) / 256, 256, 0, stream>>>(
      W0, W1, W2, W3, W4, W5, W6, W7, Wsig, W8, W9, W10, W11, W12, Wrgb);

  nerf_main<<<NB / RTILE, 256, 0, stream>>>(
      x, dd, b0, b1, b2, b3, b4, b5, b6, b7, bsig, b8, b9, b10, b11, b12, brgb,
      (float*)d_out);
}